// Round 2
// baseline (338.210 us; speedup 1.0000x reference)
//
#include <hip/hip_runtime.h>
#include <hip/hip_bf16.h>

typedef __attribute__((ext_vector_type(4))) float f32x4;
typedef __attribute__((ext_vector_type(8))) short s16x8;

constexpr int NN   = 8192;
constexpr int KIN  = 512;
constexpr int KOUT = 128;

// round-to-nearest-even f32 -> bf16 bits
__device__ __forceinline__ ushort f2bf(float x) {
    union { float f; unsigned u; } v; v.f = x;
    unsigned r = (v.u + 0x7fffu + ((v.u >> 16) & 1u)) >> 16;
    return (ushort)r;
}

// ---------------- Kernel A: h = input @ W ; hT(bf16), s, t ----------------
__global__ __launch_bounds__(256) void kA(const float* __restrict__ inp,
                                          const float* __restrict__ W,
                                          const float* __restrict__ a_s,
                                          const float* __restrict__ a_n,
                                          ushort* __restrict__ hT,
                                          float* __restrict__ s_out,
                                          float* __restrict__ t_out) {
    __shared__ float smem[16 * 512];            // 32 KB; reused as h_lds[16][128]
    const int t = threadIdx.x;
    const int rbase = blockIdx.x * 16;

    // stage 16x512 input tile
#pragma unroll
    for (int it = 0; it < 8; ++it) {
        int idx = it * 256 + t;                 // float4 units
        int r = idx >> 7;
        int c4 = (idx & 127) << 2;
        *(f32x4*)(&smem[r * 512 + c4]) =
            *(const f32x4*)(inp + (size_t)(rbase + r) * KIN + c4);
    }
    __syncthreads();

    // each thread: 2 rows x 4 cols
    const int c0 = (t & 31) * 4;
    const int rg = (t >> 5) * 2;
    float acc[2][4] = {};
#pragma unroll 4
    for (int k = 0; k < KIN; ++k) {
        f32x4 w4 = *(const f32x4*)(W + (size_t)k * KOUT + c0);
        float a0 = smem[(rg + 0) * 512 + k];
        float a1 = smem[(rg + 1) * 512 + k];
#pragma unroll
        for (int cc = 0; cc < 4; ++cc) {
            acc[0][cc] += a0 * w4[cc];
            acc[1][cc] += a1 * w4[cc];
        }
    }
    __syncthreads();

    float* h_lds = smem;                        // [16][128]
#pragma unroll
    for (int rr = 0; rr < 2; ++rr) {
        f32x4 v = {acc[rr][0], acc[rr][1], acc[rr][2], acc[rr][3]};
        *(f32x4*)(&h_lds[(rg + rr) * 128 + c0]) = v;
    }
    __syncthreads();

    // transposed bf16 write: thread -> (col = t>>1, 8 rows)
    {
        const int col = t >> 1;
        const int r0 = (t & 1) * 8;
        ushort tmp[8];
#pragma unroll
        for (int rr = 0; rr < 8; ++rr) tmp[rr] = f2bf(h_lds[(r0 + rr) * 128 + col]);
        *(f32x4*)(hT + (size_t)col * NN + rbase + r0) = *(f32x4*)&tmp[0];
    }

    // s,t: per-wave row dots with shuffle reduce (4 rows per wave)
    {
        const int w = t >> 6, lane = t & 63;
        float as1 = a_s[lane], as2 = a_s[64 + lane];
        float an1 = a_n[lane], an2 = a_n[64 + lane];
#pragma unroll
        for (int rr = 0; rr < 4; ++rr) {
            int row = w * 4 + rr;
            float h1 = h_lds[row * 128 + lane];
            float h2 = h_lds[row * 128 + 64 + lane];
            float ps = h1 * as1 + h2 * as2;
            float pt = h1 * an1 + h2 * an2;
#pragma unroll
            for (int off = 32; off; off >>= 1) {
                ps += __shfl_xor(ps, off);
                pt += __shfl_xor(pt, off);
            }
            if (lane == 0) {
                s_out[rbase + row] = ps;
                t_out[rbase + row] = pt;
            }
        }
    }
}

// ---------------- Kernel B: fused mask/lrelu/exp + PV via MFMA ----------------
// grid 128*JCHUNK: bid -> rb = bid/JCHUNK, jc = bid%JCHUNK
// block 256 = 4 waves, wave w owns rows rb*64 + w*16 .. +15
#define LOAD_SET(m0, m1, d0, d1, tt0, tt1, OFF)          \
    m0  = *(const f32x4*)(Mp + (OFF));                   \
    m1  = *(const f32x4*)(Mp + (OFF) + 4);               \
    d0  = *(const f32x4*)(Ap + (OFF));                   \
    d1  = *(const f32x4*)(Ap + (OFF) + 4);               \
    tt0 = *(const f32x4*)(Tp + (OFF));                   \
    tt1 = *(const f32x4*)(Tp + (OFF) + 4);

#define COMPUTE_SET(m0, m1, d0, d1, tt0, tt1, OFF) {     \
    float pv[8];                                         \
    _Pragma("unroll")                                    \
    for (int e = 0; e < 4; ++e) {                        \
        float x = (si + tt0[e]) * m0[e];                 \
        x = x > 0.f ? x : 0.2f * x;                      \
        pv[e] = d0[e] > 0.f ? __expf(x) : 0.f;           \
    }                                                    \
    _Pragma("unroll")                                    \
    for (int e = 0; e < 4; ++e) {                        \
        float x = (si + tt1[e]) * m1[e];                 \
        x = x > 0.f ? x : 0.2f * x;                      \
        pv[4 + e] = d1[e] > 0.f ? __expf(x) : 0.f;       \
    }                                                    \
    lsum += ((pv[0] + pv[1]) + (pv[2] + pv[3])) +        \
            ((pv[4] + pv[5]) + (pv[6] + pv[7]));         \
    s16x8 afrag;                                         \
    _Pragma("unroll")                                    \
    for (int e = 0; e < 8; ++e) afrag[e] = (short)f2bf(pv[e]); \
    _Pragma("unroll")                                    \
    for (int ct = 0; ct < 8; ++ct) {                     \
        s16x8 bfrag = *(const s16x8*)(Hp + (size_t)ct * 16 * NN + (OFF)); \
        acc[ct] = __builtin_amdgcn_mfma_f32_16x16x32_bf16(afrag, bfrag, acc[ct], 0, 0, 0); \
    } }

template <int JCHUNK>
__global__ __launch_bounds__(256) void kB(const float* __restrict__ Mmat,
                                          const float* __restrict__ adjm,
                                          const ushort* __restrict__ hT,
                                          const float* __restrict__ s_in,
                                          const float* __restrict__ t_in,
                                          float* __restrict__ o_part,
                                          float* __restrict__ l_part) {
    constexpr int JLEN = NN / JCHUNK;
    const int bid = blockIdx.x;
    const int rb = bid / JCHUNK;
    const int jc = bid % JCHUNK;
    const int tid = threadIdx.x;
    const int w = tid >> 6;
    const int lane = tid & 63;
    const int lrow = lane & 15;          // A-frag row
    const int kgrp = lane >> 4;          // A-frag k-group
    const int i = rb * 64 + w * 16 + lrow;
    const float si = s_in[i];
    const int j0 = jc * JLEN;

    const float*  Mp = Mmat + (size_t)i * NN + j0 + kgrp * 8;
    const float*  Ap = adjm + (size_t)i * NN + j0 + kgrp * 8;
    const float*  Tp = t_in + j0 + kgrp * 8;
    const ushort* Hp = hT + (size_t)lrow * NN + j0 + kgrp * 8;

    f32x4 acc[8];
#pragma unroll
    for (int ct = 0; ct < 8; ++ct) acc[ct] = (f32x4){0.f, 0.f, 0.f, 0.f};
    float lsum = 0.f;

    // depth-2 software pipeline, two named register sets (a/b)
    f32x4 ma0, ma1, da0, da1, ta0, ta1;
    f32x4 mb0, mb1, db0, db1, tb0, tb1;
    LOAD_SET(ma0, ma1, da0, da1, ta0, ta1, 0)

    for (int off = 0; off < JLEN; off += 64) {
        LOAD_SET(mb0, mb1, db0, db1, tb0, tb1, off + 32)
        COMPUTE_SET(ma0, ma1, da0, da1, ta0, ta1, off)
        int offn = off + 64;
        if (offn >= JLEN) offn = 0;      // dead prefetch on last trip (never consumed)
        LOAD_SET(ma0, ma1, da0, da1, ta0, ta1, offn)
        COMPUTE_SET(mb0, mb1, db0, db1, tb0, tb1, off + 32)
    }

    // denominator: lanes {l, l^16, l^32, l^48} share a row
    lsum += __shfl_xor(lsum, 16);
    lsum += __shfl_xor(lsum, 32);
    if (lane < 16) l_part[(size_t)jc * NN + i] = lsum;

    // store o partials (D layout: row=(lane>>4)*4+reg, col=lane&15)
    float* op = o_part + (size_t)jc * NN * KOUT;
#pragma unroll
    for (int ct = 0; ct < 8; ++ct) {
#pragma unroll
        for (int r = 0; r < 4; ++r) {
            int gi = rb * 64 + w * 16 + kgrp * 4 + r;
            int col = ct * 16 + lrow;
            op[(size_t)gi * KOUT + col] = acc[ct][r];
        }
    }
}

// ---------------- Kernel C: reduce partials, divide, ELU ----------------
template <int P>
__global__ __launch_bounds__(256) void kC(const float* __restrict__ o_part,
                                          const float* __restrict__ l_part,
                                          float* __restrict__ out) {
    const int idx = blockIdx.x * 256 + threadIdx.x;   // 0 .. 1M-1
    const int i = idx >> 7;
    float osum = 0.f, lsum = 0.f;
#pragma unroll
    for (int p = 0; p < P; ++p) {
        osum += o_part[(size_t)p * NN * KOUT + idx];
        lsum += l_part[(size_t)p * NN + i];
    }
    float v = osum / lsum;
    out[idx] = v > 0.f ? v : (__expf(v) - 1.f);
}

extern "C" void kernel_launch(void* const* d_in, const int* in_sizes, int n_in,
                              void* d_out, int out_size, void* d_ws, size_t ws_size,
                              hipStream_t stream) {
    const float* inp = (const float*)d_in[0];
    const float* adj = (const float*)d_in[1];
    const float* Mm  = (const float*)d_in[2];
    const float* W   = (const float*)d_in[3];
    const float* a_s = (const float*)d_in[4];
    const float* a_n = (const float*)d_in[5];
    float* out = (float*)d_out;

    char* ws = (char*)d_ws;
    ushort* hT    = (ushort*)(ws + 0);              //  2 MB  [128][8192] bf16
    float*  s_buf = (float*)(ws + 2097152);         // 32 KB
    float*  t_buf = (float*)(ws + 2129920);         // 32 KB
    float*  l_prt = (float*)(ws + 2162688);         // up to 256 KB [P][8192]
    float*  o_prt = (float*)(ws + 4194304);         // P * 4 MB [P][8192][128]

    hipLaunchKernelGGL(kA, dim3(512), dim3(256), 0, stream, inp, W, a_s, a_n, hT, s_buf, t_buf);

    const size_t need8 = 4194304ull + 8ull * NN * KOUT * 4ull;
    if (ws_size >= need8) {
        hipLaunchKernelGGL((kB<8>), dim3(128 * 8), dim3(256), 0, stream, Mm, adj, hT, s_buf, t_buf, o_prt, l_prt);
        hipLaunchKernelGGL((kC<8>), dim3(4096), dim3(256), 0, stream, o_prt, l_prt, out);
    } else {
        hipLaunchKernelGGL((kB<4>), dim3(128 * 4), dim3(256), 0, stream, Mm, adj, hT, s_buf, t_buf, o_prt, l_prt);
        hipLaunchKernelGGL((kC<4>), dim3(4096), dim3(256), 0, stream, o_prt, l_prt, out);
    }
}

// Round 3
// 330.287 us; speedup vs baseline: 1.0240x; 1.0240x over previous
//
#include <hip/hip_runtime.h>
#include <hip/hip_bf16.h>

typedef __attribute__((ext_vector_type(4))) float f32x4;
typedef __attribute__((ext_vector_type(8))) short s16x8;

constexpr int NN   = 8192;
constexpr int KIN  = 512;
constexpr int KOUT = 128;

constexpr int JCHUNK = 4;
constexpr int JLEN   = NN / JCHUNK;   // 2048
constexpr int SG     = 128;           // stage width (cols)
constexpr int NS     = JLEN / SG;     // 16 stages

// round-to-nearest-even f32 -> bf16 bits
__device__ __forceinline__ ushort f2bf(float x) {
    union { float f; unsigned u; } v; v.f = x;
    unsigned r = (v.u + 0x7fffu + ((v.u >> 16) & 1u)) >> 16;
    return (ushort)r;
}

__device__ __forceinline__ void gload_lds16(const ushort* g, ushort* l) {
    __builtin_amdgcn_global_load_lds((const __attribute__((address_space(1))) void*)g,
                                     (__attribute__((address_space(3))) void*)l, 16, 0, 0);
}

// ---------------- Kernel A: h = input @ W ; hT(bf16), s, t ----------------
__global__ __launch_bounds__(256) void kA(const float* __restrict__ inp,
                                          const float* __restrict__ W,
                                          const float* __restrict__ a_s,
                                          const float* __restrict__ a_n,
                                          ushort* __restrict__ hT,
                                          float* __restrict__ s_out,
                                          float* __restrict__ t_out) {
    __shared__ float smem[16 * 512];            // 32 KB; reused as h_lds[16][128]
    const int t = threadIdx.x;
    const int rbase = blockIdx.x * 16;

#pragma unroll
    for (int it = 0; it < 8; ++it) {
        int idx = it * 256 + t;
        int r = idx >> 7;
        int c4 = (idx & 127) << 2;
        *(f32x4*)(&smem[r * 512 + c4]) =
            *(const f32x4*)(inp + (size_t)(rbase + r) * KIN + c4);
    }
    __syncthreads();

    const int c0 = (t & 31) * 4;
    const int rg = (t >> 5) * 2;
    float acc[2][4] = {};
#pragma unroll 4
    for (int k = 0; k < KIN; ++k) {
        f32x4 w4 = *(const f32x4*)(W + (size_t)k * KOUT + c0);
        float a0 = smem[(rg + 0) * 512 + k];
        float a1 = smem[(rg + 1) * 512 + k];
#pragma unroll
        for (int cc = 0; cc < 4; ++cc) {
            acc[0][cc] += a0 * w4[cc];
            acc[1][cc] += a1 * w4[cc];
        }
    }
    __syncthreads();

    float* h_lds = smem;                        // [16][128]
#pragma unroll
    for (int rr = 0; rr < 2; ++rr) {
        f32x4 v = {acc[rr][0], acc[rr][1], acc[rr][2], acc[rr][3]};
        *(f32x4*)(&h_lds[(rg + rr) * 128 + c0]) = v;
    }
    __syncthreads();

    {
        const int col = t >> 1;
        const int r0 = (t & 1) * 8;
        ushort tmp[8];
#pragma unroll
        for (int rr = 0; rr < 8; ++rr) tmp[rr] = f2bf(h_lds[(r0 + rr) * 128 + col]);
        *(f32x4*)(hT + (size_t)col * NN + rbase + r0) = *(f32x4*)&tmp[0];
    }

    {
        const int w = t >> 6, lane = t & 63;
        float as1 = a_s[lane], as2 = a_s[64 + lane];
        float an1 = a_n[lane], an2 = a_n[64 + lane];
#pragma unroll
        for (int rr = 0; rr < 4; ++rr) {
            int row = w * 4 + rr;
            float h1 = h_lds[row * 128 + lane];
            float h2 = h_lds[row * 128 + 64 + lane];
            float ps = h1 * as1 + h2 * as2;
            float pt = h1 * an1 + h2 * an2;
#pragma unroll
            for (int off = 32; off; off >>= 1) {
                ps += __shfl_xor(ps, off);
                pt += __shfl_xor(pt, off);
            }
            if (lane == 0) {
                s_out[rbase + row] = ps;
                t_out[rbase + row] = pt;
            }
        }
    }
}

// ---------------- Kernel B v3 ----------------
// grid 512: rb = bid>>2 (64-row block), jc = bid&3 (2048-col chunk)
// 4 waves; wave w owns rows rb*64 + w*16 .. +15.
// Pipeline per 128-col stage: coalesced M/adj -> regs (next stage),
// hT -> LDS via global_load_lds (next stage), exp+pack -> P_lds -> MFMA (this stage).

struct Stage { f32x4 m[4][2]; f32x4 a[4][2]; };

__global__ __launch_bounds__(256, 2) void kB(const float* __restrict__ Mmat,
                                             const float* __restrict__ adjm,
                                             const ushort* __restrict__ hT,
                                             const float* __restrict__ s_in,
                                             const float* __restrict__ t_in,
                                             float* __restrict__ o_part,
                                             float* __restrict__ l_part) {
    __shared__ ushort htb[2][128 * 128];        // 64 KB double-buffered hT tile
    __shared__ ushort Pl[4][16 * 128];          // 16 KB per-wave P tiles

    const int bid = blockIdx.x;
    const int rb = bid >> 2;
    const int jc = bid & 3;
    const int tid = threadIdx.x;
    const int w = tid >> 6;
    const int l = tid & 63;
    const int lrow = l & 15;
    const int kgrp = l >> 4;
    const int j0 = jc * JLEN;

    // producer rows: pr(r4) = rb*64 + w*16 + r4*4 + kgrp ; producer cols: lrow*4 + g*64
    float sreg[4];
#pragma unroll
    for (int r4 = 0; r4 < 4; ++r4) sreg[r4] = s_in[rb * 64 + w * 16 + r4 * 4 + kgrp];

    const float* Mp[4];
    const float* Ap[4];
#pragma unroll
    for (int r4 = 0; r4 < 4; ++r4) {
        size_t ro = (size_t)(rb * 64 + w * 16 + r4 * 4 + kgrp) * NN + j0 + lrow * 4;
        Mp[r4] = Mmat + ro;
        Ap[r4] = adjm + ro;
    }
    const float* tp = t_in + j0 + lrow * 4;

    // hT staging sources: wave w stages rows w*32..w*32+31; pre-swizzled col group
    const ushort* Hp[8];
#pragma unroll
    for (int q = 0; q < 8; ++q) {
        int rphys = w * 32 + q * 4 + kgrp;
        int ql = lrow ^ (rphys & 7);
        Hp[q] = hT + (size_t)rphys * NN + j0 + ql * 8;
    }

    f32x4 acc[8];
#pragma unroll
    for (int ct = 0; ct < 8; ++ct) acc[ct] = (f32x4){0.f, 0.f, 0.f, 0.f};
    float lsum[4] = {0.f, 0.f, 0.f, 0.f};

#define LOADSET(S, FOFF)                                                        \
    _Pragma("unroll") for (int r4 = 0; r4 < 4; ++r4) {                          \
        _Pragma("unroll") for (int g = 0; g < 2; ++g) {                         \
            (S).m[r4][g] = *(const f32x4*)(Mp[r4] + (FOFF) + g * 64);           \
            (S).a[r4][g] = *(const f32x4*)(Ap[r4] + (FOFF) + g * 64);           \
        }                                                                       \
    }

#define HTISSUE(BUF, SOFF)                                                      \
    _Pragma("unroll") for (int q = 0; q < 8; ++q)                               \
        gload_lds16(Hp[q] + (SOFF), (BUF) + (w * 32 + q * 4) * 128);

#define ADVANCE()                                                               \
    {                                                                           \
        _Pragma("unroll") for (int r4 = 0; r4 < 4; ++r4) { Mp[r4] += SG; Ap[r4] += SG; } \
        _Pragma("unroll") for (int q = 0; q < 8; ++q) Hp[q] += SG;              \
        tp += SG;                                                               \
    }

#define COMPUTE(S, BUF, T0, T1)                                                 \
    {                                                                           \
        _Pragma("unroll") for (int r4 = 0; r4 < 4; ++r4) {                      \
            const int prow = r4 * 4 + kgrp;                                     \
            uint ow[4];                                                         \
            _Pragma("unroll") for (int g = 0; g < 2; ++g) {                     \
                f32x4 tv = g ? (T1) : (T0);                                     \
                f32x4 mv = (S).m[r4][g];                                        \
                f32x4 av = (S).a[r4][g];                                        \
                float pv[4];                                                    \
                _Pragma("unroll") for (int e = 0; e < 4; ++e) {                 \
                    float x = (sreg[r4] + tv[e]) * mv[e];                       \
                    x = x > 0.f ? x : 0.2f * x;                                 \
                    float p = av[e] > 0.f ? __expf(x) : 0.f;                    \
                    lsum[r4] += p;                                              \
                    pv[e] = p;                                                  \
                }                                                               \
                ow[g * 2 + 0] = (uint)f2bf(pv[0]) | ((uint)f2bf(pv[1]) << 16);  \
                ow[g * 2 + 1] = (uint)f2bf(pv[2]) | ((uint)f2bf(pv[3]) << 16);  \
            }                                                                   \
            int b0 = (prow * 256 + lrow * 8) ^ ((prow & 7) << 4);               \
            int b1 = (prow * 256 + lrow * 8 + 128) ^ ((prow & 7) << 4);         \
            *(uint2*)((char*)&Pl[w][0] + b0) = make_uint2(ow[0], ow[1]);        \
            *(uint2*)((char*)&Pl[w][0] + b1) = make_uint2(ow[2], ow[3]);        \
        }                                                                       \
        s16x8 af[4];                                                            \
        _Pragma("unroll") for (int ks = 0; ks < 4; ++ks) {                      \
            int b = (lrow * 256 + ks * 64 + kgrp * 16) ^ ((lrow & 7) << 4);     \
            af[ks] = *(s16x8*)((char*)&Pl[w][0] + b);                           \
        }                                                                       \
        _Pragma("unroll") for (int ks = 0; ks < 4; ++ks) {                      \
            _Pragma("unroll") for (int ct = 0; ct < 8; ++ct) {                  \
                int f = ct * 16 + lrow;                                         \
                int b = (f * 256 + ks * 64 + kgrp * 16) ^ ((f & 7) << 4);       \
                s16x8 bf = *(const s16x8*)((const char*)(BUF) + b);             \
                acc[ct] = __builtin_amdgcn_mfma_f32_16x16x32_bf16(af[ks], bf, acc[ct], 0, 0, 0); \
            }                                                                   \
        }                                                                       \
    }

    Stage sa, sb;
    // prologue: stage 0 data
    LOADSET(sa, 0)
    HTISSUE(htb[0], 0)
    __syncthreads();

    for (int s = 0; s < NS; s += 2) {
        // even stage: consume sa/htb0, prefetch sb/htb1
        f32x4 t0 = *(const f32x4*)(tp);
        f32x4 t1 = *(const f32x4*)(tp + 64);
        LOADSET(sb, SG)
        HTISSUE(htb[1], SG)
        ADVANCE()
        COMPUTE(sa, htb[0], t0, t1)
        __syncthreads();

        // odd stage: consume sb/htb1, prefetch sa/htb0
        t0 = *(const f32x4*)(tp);
        t1 = *(const f32x4*)(tp + 64);
        if (s + 2 < NS) {
            LOADSET(sa, SG)
            HTISSUE(htb[0], SG)
        }
        ADVANCE()
        COMPUTE(sb, htb[1], t0, t1)
        __syncthreads();
    }

    // denominator: reduce over the 16 lanes sharing kgrp (lrow 0..15)
#pragma unroll
    for (int r4 = 0; r4 < 4; ++r4) {
#pragma unroll
        for (int off = 1; off < 16; off <<= 1) lsum[r4] += __shfl_xor(lsum[r4], off);
        if (lrow == 0) l_part[(size_t)jc * NN + rb * 64 + w * 16 + r4 * 4 + kgrp] = lsum[r4];
    }

    // o partials (D layout: row=(lane>>4)*4+reg, col=lane&15)
    float* op = o_part + (size_t)jc * NN * KOUT;
#pragma unroll
    for (int ct = 0; ct < 8; ++ct) {
#pragma unroll
        for (int r = 0; r < 4; ++r) {
            int gi = rb * 64 + w * 16 + kgrp * 4 + r;
            int col = ct * 16 + lrow;
            op[(size_t)gi * KOUT + col] = acc[ct][r];
        }
    }
#undef LOADSET
#undef HTISSUE
#undef ADVANCE
#undef COMPUTE
}

// ---------------- Kernel C: reduce partials, divide, ELU ----------------
template <int P>
__global__ __launch_bounds__(256) void kC(const float* __restrict__ o_part,
                                          const float* __restrict__ l_part,
                                          float* __restrict__ out) {
    const int idx = blockIdx.x * 256 + threadIdx.x;
    const int i = idx >> 7;
    float osum = 0.f, lsum = 0.f;
#pragma unroll
    for (int p = 0; p < P; ++p) {
        osum += o_part[(size_t)p * NN * KOUT + idx];
        lsum += l_part[(size_t)p * NN + i];
    }
    float v = osum / lsum;
    out[idx] = v > 0.f ? v : (__expf(v) - 1.f);
}

extern "C" void kernel_launch(void* const* d_in, const int* in_sizes, int n_in,
                              void* d_out, int out_size, void* d_ws, size_t ws_size,
                              hipStream_t stream) {
    const float* inp = (const float*)d_in[0];
    const float* adj = (const float*)d_in[1];
    const float* Mm  = (const float*)d_in[2];
    const float* W   = (const float*)d_in[3];
    const float* a_s = (const float*)d_in[4];
    const float* a_n = (const float*)d_in[5];
    float* out = (float*)d_out;

    char* ws = (char*)d_ws;
    ushort* hT    = (ushort*)(ws + 0);              //  2 MB  [128][8192] bf16
    float*  s_buf = (float*)(ws + 2097152);         // 32 KB
    float*  t_buf = (float*)(ws + 2129920);         // 32 KB
    float*  l_prt = (float*)(ws + 2162688);         // 128 KB [4][8192]
    float*  o_prt = (float*)(ws + 4194304);         // 16 MB  [4][8192][128]

    hipLaunchKernelGGL(kA, dim3(512), dim3(256), 0, stream, inp, W, a_s, a_n, hT, s_buf, t_buf);
    hipLaunchKernelGGL(kB, dim3(128 * JCHUNK), dim3(256), 0, stream, Mm, adj, hT, s_buf, t_buf, o_prt, l_prt);
    hipLaunchKernelGGL((kC<JCHUNK>), dim3(4096), dim3(256), 0, stream, o_prt, l_prt, out);
}

// Round 4
// 211.242 us; speedup vs baseline: 1.6011x; 1.5635x over previous
//
#include <hip/hip_runtime.h>
#include <hip/hip_bf16.h>

typedef __attribute__((ext_vector_type(4))) float f32x4;
typedef __attribute__((ext_vector_type(8))) short s16x8;

constexpr int NN   = 8192;
constexpr int KIN  = 512;
constexpr int KOUT = 128;

constexpr int JCHUNK = 4;
constexpr int JLEN   = NN / JCHUNK;   // 2048
constexpr int SG     = 32;            // stage width (cols)
constexpr int NS     = JLEN / SG;     // 64 stages
// LDS byte map: buf k at k*24576 = {M 8KB | adj 8KB | hT 8KB}; t-chunk at 73728 (8KB)
constexpr int BUFSTRIDE = 24576;
constexpr int A_OFF = 8192;
constexpr int H_OFF = 16384;
constexpr int T_OFF = 73728;

// round-to-nearest-even f32 -> bf16 bits
__device__ __forceinline__ ushort f2bf(float x) {
    union { float f; unsigned u; } v; v.f = x;
    unsigned r = (v.u + 0x7fffu + ((v.u >> 16) & 1u)) >> 16;
    return (ushort)r;
}

__device__ __forceinline__ void gload_lds16(const void* g, void* l) {
    __builtin_amdgcn_global_load_lds((const __attribute__((address_space(1))) void*)g,
                                     (__attribute__((address_space(3))) void*)l, 16, 0, 0);
}

// ---------------- Kernel A: h = input @ W ; hT(bf16), s, t ----------------
__global__ __launch_bounds__(256) void kA(const float* __restrict__ inp,
                                          const float* __restrict__ W,
                                          const float* __restrict__ a_s,
                                          const float* __restrict__ a_n,
                                          ushort* __restrict__ hT,
                                          float* __restrict__ s_out,
                                          float* __restrict__ t_out) {
    __shared__ float smem[16 * 512];            // 32 KB; reused as h_lds[16][128]
    const int t = threadIdx.x;
    const int rbase = blockIdx.x * 16;

#pragma unroll
    for (int it = 0; it < 8; ++it) {
        int idx = it * 256 + t;
        int r = idx >> 7;
        int c4 = (idx & 127) << 2;
        *(f32x4*)(&smem[r * 512 + c4]) =
            *(const f32x4*)(inp + (size_t)(rbase + r) * KIN + c4);
    }
    __syncthreads();

    const int c0 = (t & 31) * 4;
    const int rg = (t >> 5) * 2;
    float acc[2][4] = {};
#pragma unroll 4
    for (int k = 0; k < KIN; ++k) {
        f32x4 w4 = *(const f32x4*)(W + (size_t)k * KOUT + c0);
        float a0 = smem[(rg + 0) * 512 + k];
        float a1 = smem[(rg + 1) * 512 + k];
#pragma unroll
        for (int cc = 0; cc < 4; ++cc) {
            acc[0][cc] += a0 * w4[cc];
            acc[1][cc] += a1 * w4[cc];
        }
    }
    __syncthreads();

    float* h_lds = smem;                        // [16][128]
#pragma unroll
    for (int rr = 0; rr < 2; ++rr) {
        f32x4 v = {acc[rr][0], acc[rr][1], acc[rr][2], acc[rr][3]};
        *(f32x4*)(&h_lds[(rg + rr) * 128 + c0]) = v;
    }
    __syncthreads();

    {
        const int col = t >> 1;
        const int r0 = (t & 1) * 8;
        ushort tmp[8];
#pragma unroll
        for (int rr = 0; rr < 8; ++rr) tmp[rr] = f2bf(h_lds[(r0 + rr) * 128 + col]);
        *(f32x4*)(hT + (size_t)col * NN + rbase + r0) = *(f32x4*)&tmp[0];
    }

    {
        const int w = t >> 6, lane = t & 63;
        float as1 = a_s[lane], as2 = a_s[64 + lane];
        float an1 = a_n[lane], an2 = a_n[64 + lane];
#pragma unroll
        for (int rr = 0; rr < 4; ++rr) {
            int row = w * 4 + rr;
            float h1 = h_lds[row * 128 + lane];
            float h2 = h_lds[row * 128 + 64 + lane];
            float ps = h1 * as1 + h2 * as2;
            float pt = h1 * an1 + h2 * an2;
#pragma unroll
            for (int off = 32; off; off >>= 1) {
                ps += __shfl_xor(ps, off);
                pt += __shfl_xor(pt, off);
            }
            if (lane == 0) {
                s_out[rbase + row] = ps;
                t_out[rbase + row] = pt;
            }
        }
    }
}

// ---------------- Kernel B v4: global_load_lds ring-3 + counted vmcnt ----------------
// grid 512: rb = bid>>2 (64 rows), jc = bid&3 (2048 cols). 4 waves; wave w rows w*16..+15.
// Per stage per wave: 6 gload_lds issues (M x2, adj x2, hT x2). vmcnt(6) keeps 2 stages in flight.
__global__ __launch_bounds__(256, 2) void kB(const float* __restrict__ Mmat,
                                             const float* __restrict__ adjm,
                                             const ushort* __restrict__ hT,
                                             const float* __restrict__ s_in,
                                             const float* __restrict__ t_in,
                                             float* __restrict__ o_part,
                                             float* __restrict__ l_part) {
    __shared__ f32x4 LDSQ[81920 / 16];
    char* LDS = (char*)LDSQ;

    const int tid = threadIdx.x;
    const int w = tid >> 6;
    const int l = tid & 63;
    const int lrow = l & 15;             // MFMA A-row this lane owns
    const int kgrp = l >> 4;             // MFMA k-group
    const int rb = blockIdx.x >> 2;
    const int jc = blockIdx.x & 3;
    const int j0 = jc * JLEN;

    // ---- t-chunk preload into LDS (2048 f32, broadcast-read later) ----
    {
        const float* tp = t_in + j0 + tid * 8;
        f32x4 a = *(const f32x4*)tp;
        f32x4 b = *(const f32x4*)(tp + 4);
        *(f32x4*)(LDS + T_OFF + tid * 32) = a;
        *(f32x4*)(LDS + T_OFF + tid * 32 + 16) = b;
    }
    asm volatile("s_waitcnt lgkmcnt(0)" ::: "memory");

    const float si = s_in[rb * 64 + w * 16 + lrow];

    // ---- staging source pointers (pre-swizzled global source, linear LDS dst) ----
    // M/adj: instr covers 8 rows x 8 chunks(16B); lane λ: row λ>>3, fetch chunk (λ&7)^(λ>>3)
    const int rl8 = l >> 3, c8 = l & 7;
    const int csMA = c8 ^ rl8;
    const float* gM0 = Mmat + (size_t)(rb * 64 + w * 16 + rl8) * NN + j0 + csMA * 4;
    const float* gM1 = gM0 + (size_t)8 * NN;
    const float* gA0 = adjm + (size_t)(rb * 64 + w * 16 + rl8) * NN + j0 + csMA * 4;
    const float* gA1 = gA0 + (size_t)8 * NN;
    // hT: instr covers 16 rows x 4 chunks(16B); lane λ: row λ>>2, fetch chunk (λ&3)^((λ>>3)&3)
    const int rl4 = l >> 2, c4 = l & 3;
    const int csH = c4 ^ (rl8 & 3);
    const ushort* gH0 = hT + (size_t)(w * 32 + rl4) * NN + j0 + csH * 8;
    const ushort* gH1 = gH0 + (size_t)16 * NN;

    // LDS dst offsets (wave-uniform)
    const int mdst0 = (w * 16) * 128, mdst1 = (w * 16 + 8) * 128;
    const int hdst0 = (w * 32) * 64, hdst1 = (w * 32 + 16) * 64;

    // per-thread constant LDS read offsets (swizzled)
    const int Cm0 = (w * 16 + lrow) * 128 + (((kgrp * 2 + 0) ^ (lrow & 7)) << 4);
    const int Cm1 = (w * 16 + lrow) * 128 + (((kgrp * 2 + 1) ^ (lrow & 7)) << 4);
    const int Ch  = lrow * 64 + ((kgrp ^ ((lrow >> 1) & 3)) << 4);

    f32x4 acc[8];
#pragma unroll
    for (int ct = 0; ct < 8; ++ct) acc[ct] = (f32x4){0.f, 0.f, 0.f, 0.f};
    float lsum = 0.f;

#define ISSUE(BB)                                                  \
    gload_lds16(gM0, LDS + (BB) + mdst0);                          \
    gload_lds16(gM1, LDS + (BB) + mdst1);                          \
    gload_lds16(gA0, LDS + (BB) + A_OFF + mdst0);                  \
    gload_lds16(gA1, LDS + (BB) + A_OFF + mdst1);                  \
    gload_lds16(gH0, LDS + (BB) + H_OFF + hdst0);                  \
    gload_lds16(gH1, LDS + (BB) + H_OFF + hdst1);

#define ADV()                                                      \
    gM0 += SG; gM1 += SG; gA0 += SG; gA1 += SG; gH0 += SG; gH1 += SG;

    // prologue: stage 0 -> buf0, stage 1 -> buf1
    ISSUE(0)
    ADV()
    ISSUE(BUFSTRIDE)
    ADV()

    unsigned b0 = 0, b1 = BUFSTRIDE, b2 = 2 * BUFSTRIDE;

#pragma unroll 1
    for (int s = 0; s < NS; ++s) {
        asm volatile("s_waitcnt vmcnt(6)" ::: "memory");   // own stage-s loads landed
        __builtin_amdgcn_s_barrier();                      // all waves' stage-s landed
        asm volatile("" ::: "memory");

        ISSUE(b2)                                          // stage s+2 (dummy re-issue at tail)
        if (s + 3 < NS) { ADV() }

        // ---- compute stage s from buf b0 ----
        {
            const char* tb = LDS + T_OFF + s * 128 + kgrp * 32;
            f32x4 tv0 = *(const f32x4*)tb;
            f32x4 tv1 = *(const f32x4*)(tb + 16);
            f32x4 mv0 = *(const f32x4*)(LDS + b0 + Cm0);
            f32x4 mv1 = *(const f32x4*)(LDS + b0 + Cm1);
            f32x4 av0 = *(const f32x4*)(LDS + b0 + A_OFF + Cm0);
            f32x4 av1 = *(const f32x4*)(LDS + b0 + A_OFF + Cm1);

            s16x8 af;
#pragma unroll
            for (int e = 0; e < 4; ++e) {
                float x = (si + tv0[e]) * mv0[e];
                x = fmaxf(x, 0.2f * x);
                float p = __expf(x) * av0[e];
                lsum += p;
                af[e] = (short)f2bf(p);
            }
#pragma unroll
            for (int e = 0; e < 4; ++e) {
                float x = (si + tv1[e]) * mv1[e];
                x = fmaxf(x, 0.2f * x);
                float p = __expf(x) * av1[e];
                lsum += p;
                af[4 + e] = (short)f2bf(p);
            }

            const char* hb = LDS + b0 + H_OFF + Ch;
#pragma unroll
            for (int ct = 0; ct < 8; ++ct) {
                s16x8 bf = *(const s16x8*)(hb + ct * 1024);
                acc[ct] = __builtin_amdgcn_mfma_f32_16x16x32_bf16(af, bf, acc[ct], 0, 0, 0);
            }
        }

        unsigned bt = b0; b0 = b1; b1 = b2; b2 = bt;       // rotate ring
    }
#undef ISSUE
#undef ADV

    // denominator: lanes {l, l^16, l^32, l^48} share row lrow
    lsum += __shfl_xor(lsum, 16);
    lsum += __shfl_xor(lsum, 32);
    if (l < 16) l_part[(size_t)jc * NN + rb * 64 + w * 16 + lrow] = lsum;

    // o partials (D layout: row=(lane>>4)*4+reg, col=lane&15)
    float* op = o_part + (size_t)jc * NN * KOUT;
#pragma unroll
    for (int ct = 0; ct < 8; ++ct) {
#pragma unroll
        for (int r = 0; r < 4; ++r) {
            int gi = rb * 64 + w * 16 + kgrp * 4 + r;
            int col = ct * 16 + lrow;
            op[(size_t)gi * KOUT + col] = acc[ct][r];
        }
    }
}

// ---------------- Kernel C: reduce partials, divide, ELU ----------------
__global__ __launch_bounds__(256) void kC(const float* __restrict__ o_part,
                                          const float* __restrict__ l_part,
                                          float* __restrict__ out) {
    const int idx = blockIdx.x * 256 + threadIdx.x;
    const int i = idx >> 7;
    float osum = 0.f, lsum = 0.f;
#pragma unroll
    for (int p = 0; p < JCHUNK; ++p) {
        osum += o_part[(size_t)p * NN * KOUT + idx];
        lsum += l_part[(size_t)p * NN + i];
    }
    float v = osum / lsum;
    out[idx] = v > 0.f ? v : (__expf(v) - 1.f);
}

extern "C" void kernel_launch(void* const* d_in, const int* in_sizes, int n_in,
                              void* d_out, int out_size, void* d_ws, size_t ws_size,
                              hipStream_t stream) {
    const float* inp = (const float*)d_in[0];
    const float* adj = (const float*)d_in[1];
    const float* Mm  = (const float*)d_in[2];
    const float* W   = (const float*)d_in[3];
    const float* a_s = (const float*)d_in[4];
    const float* a_n = (const float*)d_in[5];
    float* out = (float*)d_out;

    char* ws = (char*)d_ws;
    ushort* hT    = (ushort*)(ws + 0);              //  2 MB  [128][8192] bf16
    float*  s_buf = (float*)(ws + 2097152);         // 32 KB
    float*  t_buf = (float*)(ws + 2129920);         // 32 KB
    float*  l_prt = (float*)(ws + 2162688);         // 128 KB [4][8192]
    float*  o_prt = (float*)(ws + 4194304);         // 16 MB  [4][8192][128]

    hipLaunchKernelGGL(kA, dim3(512), dim3(256), 0, stream, inp, W, a_s, a_n, hT, s_buf, t_buf);
    hipLaunchKernelGGL(kB, dim3(128 * JCHUNK), dim3(256), 0, stream, Mm, adj, hT, s_buf, t_buf, o_prt, l_prt);
    hipLaunchKernelGGL(kC, dim3(4096), dim3(256), 0, stream, o_prt, l_prt, out);
}